// Round 1
// baseline (360.172 us; speedup 1.0000x reference)
//
#include <hip/hip_runtime.h>
#include <hip/hip_bf16.h>

#define T_DIM 4096
#define B_DIM 32
#define I_DIM 512
#define O_DIM 512
#define M_DIM (T_DIM * B_DIM)   // 131072
#define PARAM 0.1f

#define BM 128
#define BN 128
#define BK 64
#define STRIP 256
#define TAPS 16
#define BO (B_DIM * O_DIM)      // 16384

typedef __attribute__((ext_vector_type(8))) short bf16x8;
typedef __attribute__((ext_vector_type(4))) float f32x4;

// fp32 -> bf16 round-to-nearest-even (inputs are finite; no NaN handling needed)
__device__ __forceinline__ short f2bf(float f) {
    unsigned int u = __builtin_bit_cast(unsigned int, f);
    u = (u + 0x7fffu + ((u >> 16) & 1u)) >> 16;
    return (short)u;
}

// Stage a 128x64 fp32 tile -> bf16 into XOR-swizzled LDS ([row][k], row stride 128B,
// byte ^= (row&7)<<4 to break the 128B-stride bank conflict on ds_read_b128).
__device__ __forceinline__ void stage_tile(const float* __restrict__ src, short* lds, int tid) {
    const int srow = tid >> 3;            // 0..31
    const int scol = (tid & 7) << 3;      // 0,8,..,56
    #pragma unroll
    for (int p = 0; p < 4; ++p) {
        const int r = srow + (p << 5);
        const float* s = src + (size_t)r * I_DIM + scol;
        f32x4 v0 = *(const f32x4*)s;
        f32x4 v1 = *(const f32x4*)(s + 4);
        bf16x8 pk;
        #pragma unroll
        for (int j = 0; j < 4; ++j) {
            pk[j]     = f2bf(v0[j]);
            pk[j + 4] = f2bf(v1[j]);
        }
        int byte = (r << 7) + (scol << 1);
        byte ^= ((r & 7) << 4);
        *(bf16x8*)((char*)lds + byte) = pk;
    }
}

__global__ __launch_bounds__(256) void gemm_kernel(const float* __restrict__ X,
                                                   const float* __restrict__ W,
                                                   const float* __restrict__ bias,
                                                   float* __restrict__ Y,
                                                   float* __restrict__ halo) {
    __shared__ __align__(16) short As[BM * BK];
    __shared__ __align__(16) short Bs[BN * BK];

    const int tid = threadIdx.x;
    // XCD-chunked swizzle: 4096 blocks, 8 XCDs -> 512 consecutive per XCD, N fastest.
    const int bid = blockIdx.x;
    const int swz = (bid & 7) * 512 + (bid >> 3);
    const int bn = swz & 3;           // 0..3
    const int bm = swz >> 2;          // 0..1023
    const int row0 = bm * BM;
    const int col0 = bn * BN;

    const int lane = tid & 63;
    const int wave = tid >> 6;        // 0..3
    const int wm = wave >> 1;         // 0..1
    const int wn = wave & 1;          // 0..1

    f32x4 acc[4][4] = {};             // wave computes 64x64 (4x4 frags of 16x16)

    for (int ks = 0; ks < I_DIM / BK; ++ks) {
        const int k0 = ks * BK;
        stage_tile(X + (size_t)row0 * I_DIM + k0, As, tid);
        stage_tile(W + (size_t)col0 * I_DIM + k0, Bs, tid);
        __syncthreads();

        #pragma unroll
        for (int kk = 0; kk < 2; ++kk) {
            bf16x8 af[4], bfr[4];
            #pragma unroll
            for (int mf = 0; mf < 4; ++mf) {
                const int r = wm * 64 + mf * 16 + (lane & 15);
                int byte = (r << 7) + ((kk * 32 + ((lane >> 4) << 3)) << 1);
                byte ^= ((r & 7) << 4);
                af[mf] = *(const bf16x8*)((const char*)As + byte);
            }
            #pragma unroll
            for (int nf = 0; nf < 4; ++nf) {
                const int r = wn * 64 + nf * 16 + (lane & 15);
                int byte = (r << 7) + ((kk * 32 + ((lane >> 4) << 3)) << 1);
                byte ^= ((r & 7) << 4);
                bfr[nf] = *(const bf16x8*)((const char*)Bs + byte);
            }
            #pragma unroll
            for (int mf = 0; mf < 4; ++mf)
                #pragma unroll
                for (int nf = 0; nf < 4; ++nf)
                    acc[mf][nf] = __builtin_amdgcn_mfma_f32_16x16x32_bf16(
                        af[mf], bfr[nf], acc[mf][nf], 0, 0, 0);
        }
        __syncthreads();
    }

    // Epilogue: add bias, store Y; also store strip warm-up halo rows to ws.
    #pragma unroll
    for (int mf = 0; mf < 4; ++mf) {
        #pragma unroll
        for (int nf = 0; nf < 4; ++nf) {
            const int gcol = col0 + wn * 64 + nf * 16 + (lane & 15);
            const float bv = bias[gcol];
            #pragma unroll
            for (int j = 0; j < 4; ++j) {
                const int grow = row0 + wm * 64 + mf * 16 + ((lane >> 4) << 2) + j;
                const float val = acc[mf][nf][j] + bv;
                Y[(size_t)grow * O_DIM + gcol] = val;
                const int t = grow >> 5;   // row = t*32 + b
                if ((t & (STRIP - 1)) >= (STRIP - TAPS) && t < (T_DIM - STRIP)) {
                    const int ht = ((t >> 8) << 4) + (t & (STRIP - 1)) - (STRIP - TAPS);
                    const int bb = grow & 31;
                    halo[((size_t)ht * B_DIM + bb) * O_DIM + gcol] = val;
                }
            }
        }
    }
}

// EMA over t, in-place on Y. Strip s>0 warm-starts from 16 halo values
// (p^16 = 1e-16 -> truncation error far below fp32 resolution).
__global__ __launch_bounds__(256) void ema_kernel(float* __restrict__ Y,
                                                  const float* __restrict__ halo) {
    const int bx = blockIdx.x;            // 16*32*2 = 1024
    const int s = bx >> 6;                // strip 0..15
    const int b = (bx >> 1) & 31;
    const int o = ((bx & 1) << 8) + threadIdx.x;

    float v = 0.f;
    if (s > 0) {
        const float* h = halo + ((size_t)(s - 1) * TAPS * B_DIM + b) * O_DIM + o;
        #pragma unroll
        for (int j = 0; j < TAPS; ++j)
            v = PARAM * v + h[(size_t)j * BO];
    }
    float* y = Y + ((size_t)s * STRIP * B_DIM + b) * O_DIM + o;
    for (int i = 0; i < STRIP; i += 8) {
        float yv[8];
        #pragma unroll
        for (int j = 0; j < 8; ++j) yv[j] = y[(size_t)(i + j) * BO];
        #pragma unroll
        for (int j = 0; j < 8; ++j) { v = PARAM * v + yv[j]; yv[j] = v; }
        #pragma unroll
        for (int j = 0; j < 8; ++j) y[(size_t)(i + j) * BO] = yv[j];
    }
}

extern "C" void kernel_launch(void* const* d_in, const int* in_sizes, int n_in,
                              void* d_out, int out_size, void* d_ws, size_t ws_size,
                              hipStream_t stream) {
    const float* X    = (const float*)d_in[0];
    const float* W    = (const float*)d_in[1];
    const float* bias = (const float*)d_in[2];
    float* Y    = (float*)d_out;
    float* halo = (float*)d_ws;   // 240*32*512 floats = 15.7 MB

    gemm_kernel<<<dim3((M_DIM / BM) * (O_DIM / BN)), dim3(256), 0, stream>>>(X, W, bias, Y, halo);
    ema_kernel<<<dim3((T_DIM / STRIP) * B_DIM * (O_DIM / 256)), dim3(256), 0, stream>>>(Y, halo);
}

// Round 2
// 346.479 us; speedup vs baseline: 1.0395x; 1.0395x over previous
//
#include <hip/hip_runtime.h>
#include <hip/hip_bf16.h>

#define T_DIM 4096
#define B_DIM 32
#define I_DIM 512
#define O_DIM 512
#define M_DIM (T_DIM * B_DIM)   // 131072
#define PARAM 0.1f

#define BM 128
#define BN 128
#define BK 64
#define KSTEPS (I_DIM / BK)     // 8
#define STRIP 256
#define TAPS 16
#define BO (B_DIM * O_DIM)      // 16384

// ws layout: [halo: 240*32*512 f32 = 15,728,640 B][Wbf16: 512*512 u16 = 524,288 B]
#define HALO_BYTES (240u * 32u * 512u * 4u)

typedef __attribute__((ext_vector_type(8))) short bf16x8;
typedef __attribute__((ext_vector_type(4))) float f32x4;

// fp32 -> bf16 via hardware cvt (compiler emits v_cvt_pk_bf16_f32 for pairs)
__device__ __forceinline__ unsigned short f2bf(float f) {
    union { __hip_bfloat16 b; unsigned short u; } cv;
    cv.b = __float2bfloat16(f);
    return cv.u;
}

// --- W fp32 -> bf16 precompute (one-time per call, ~0.5 MB) ---
__global__ __launch_bounds__(256) void wcvt_kernel(const float* __restrict__ W,
                                                   unsigned short* __restrict__ Wb) {
    const int i = (blockIdx.x * 256 + threadIdx.x) * 4;
    f32x4 v = *(const f32x4*)(W + i);
    ushort4 o;
    o.x = f2bf(v[0]); o.y = f2bf(v[1]); o.z = f2bf(v[2]); o.w = f2bf(v[3]);
    *(ushort4*)(Wb + i) = o;
}

// --- B tile: bf16 W -> LDS via global_load_lds (16B), source pre-swizzled so the
// linear LDS write lands XOR-swizzled (rule #21: swizzle both sides or neither). ---
__device__ __forceinline__ void stageB(const unsigned short* __restrict__ Wb,
                                       int col0, int k0, short* BsBuf, int tid) {
    const int l = tid & 63;
    const int w = tid >> 6;
    #pragma unroll
    for (int it = 0; it < 4; ++it) {
        const int r0 = it * 32 + w * 8;      // 8 rows per wave per call
        const int r  = r0 + (l >> 3);
        const int c  = l & 7;                // 16B chunk within 128B row
        const int cc = c ^ (r & 7);          // pre-swizzled source chunk
        const unsigned short* g = Wb + (size_t)(col0 + r) * I_DIM + k0 + cc * 8;
        __builtin_amdgcn_global_load_lds(
            (const __attribute__((address_space(1))) unsigned int*)g,
            (__attribute__((address_space(3))) unsigned int*)(BsBuf + r0 * BK),
            16, 0, 0);
    }
}

// --- A tile: fp32 X -> regs (issued early), cvt+swizzled ds_write (late) ---
__device__ __forceinline__ void loadA(const float* __restrict__ X, int row0, int k0,
                                      f32x4* regs, int tid) {
    const int r = tid >> 1;
    const int h = tid & 1;
    const float* s = X + (size_t)(row0 + r) * I_DIM + k0 + h * 32;
    #pragma unroll
    for (int j = 0; j < 8; ++j) regs[j] = *(const f32x4*)(s + j * 4);
}

__device__ __forceinline__ void writeA(const f32x4* regs, short* AsBuf, int tid) {
    const int r = tid >> 1;
    const int h = tid & 1;
    #pragma unroll
    for (int j = 0; j < 4; ++j) {
        bf16x8 pk;
        #pragma unroll
        for (int e = 0; e < 4; ++e) {
            pk[e]     = (short)f2bf(regs[2 * j][e]);
            pk[e + 4] = (short)f2bf(regs[2 * j + 1][e]);
        }
        const int c  = h * 4 + j;
        const int cs = c ^ (r & 7);
        *(bf16x8*)((char*)AsBuf + r * 128 + cs * 16) = pk;
    }
}

__device__ __forceinline__ void compute(const short* As, const short* Bs,
                                        f32x4 acc[4][4], int lane, int wm, int wn) {
    #pragma unroll
    for (int kk = 0; kk < 2; ++kk) {
        bf16x8 af[4], bfr[4];
        #pragma unroll
        for (int mf = 0; mf < 4; ++mf) {
            const int r = wm * 64 + mf * 16 + (lane & 15);
            int byte = (r << 7) + ((kk * 32 + ((lane >> 4) << 3)) << 1);
            byte ^= ((r & 7) << 4);
            af[mf] = *(const bf16x8*)((const char*)As + byte);
        }
        #pragma unroll
        for (int nf = 0; nf < 4; ++nf) {
            const int r = wn * 64 + nf * 16 + (lane & 15);
            int byte = (r << 7) + ((kk * 32 + ((lane >> 4) << 3)) << 1);
            byte ^= ((r & 7) << 4);
            bfr[nf] = *(const bf16x8*)((const char*)Bs + byte);
        }
        #pragma unroll
        for (int mf = 0; mf < 4; ++mf)
            #pragma unroll
            for (int nf = 0; nf < 4; ++nf)
                acc[mf][nf] = __builtin_amdgcn_mfma_f32_16x16x32_bf16(
                    af[mf], bfr[nf], acc[mf][nf], 0, 0, 0);
    }
}

__global__ __launch_bounds__(256) void gemm_kernel(const float* __restrict__ X,
                                                   const unsigned short* __restrict__ Wb,
                                                   const float* __restrict__ bias,
                                                   float* __restrict__ Y,
                                                   float* __restrict__ halo) {
    __shared__ __align__(16) short As[2][BM * BK];
    __shared__ __align__(16) short Bs[2][BN * BK];

    const int tid = threadIdx.x;
    // XCD-chunked swizzle: 4096 blocks, 8 XCDs, N fastest within a chunk.
    const int bid = blockIdx.x;
    const int swz = (bid & 7) * 512 + (bid >> 3);
    const int bn = swz & 3;
    const int bm = swz >> 2;
    const int row0 = bm * BM;
    const int col0 = bn * BN;

    const int lane = tid & 63;
    const int wm = (tid >> 6) >> 1;
    const int wn = (tid >> 6) & 1;

    f32x4 acc[4][4] = {};
    f32x4 aregs[8];

    // prologue: stage tile 0
    stageB(Wb, col0, 0, &Bs[0][0], tid);
    loadA(X, row0, 0, aregs, tid);
    writeA(aregs, &As[0][0], tid);
    __syncthreads();

    #pragma unroll
    for (int ks = 0; ks < KSTEPS; ++ks) {
        const int cur = ks & 1;
        const int nxt = cur ^ 1;
        if (ks < KSTEPS - 1) {
            stageB(Wb, col0, (ks + 1) * BK, &Bs[nxt][0], tid);   // async, drains at barrier
            loadA(X, row0, (ks + 1) * BK, aregs, tid);           // issue early (T14)
        }
        compute(&As[cur][0], &Bs[cur][0], acc, lane, wm, wn);
        if (ks < KSTEPS - 1)
            writeA(aregs, &As[nxt][0], tid);                     // write late (T14)
        __syncthreads();
    }

    // Epilogue: bias add, Y store, strip warm-up halo rows to ws.
    #pragma unroll
    for (int mf = 0; mf < 4; ++mf) {
        #pragma unroll
        for (int nf = 0; nf < 4; ++nf) {
            const int gcol = col0 + wn * 64 + nf * 16 + (lane & 15);
            const float bv = bias[gcol];
            #pragma unroll
            for (int j = 0; j < 4; ++j) {
                const int grow = row0 + wm * 64 + mf * 16 + ((lane >> 4) << 2) + j;
                const float val = acc[mf][nf][j] + bv;
                Y[(size_t)grow * O_DIM + gcol] = val;
                const int t = grow >> 5;   // row = t*32 + b
                if ((t & (STRIP - 1)) >= (STRIP - TAPS) && t < (T_DIM - STRIP)) {
                    const int ht = ((t >> 8) << 4) + (t & (STRIP - 1)) - (STRIP - TAPS);
                    const int bb = grow & 31;
                    halo[((size_t)ht * B_DIM + bb) * O_DIM + gcol] = val;
                }
            }
        }
    }
}

// EMA over t, in-place on Y. Strip s>0 warm-starts from 16 halo rows
// (p^16 = 1e-16 -> truncation error far below fp32 resolution).
__global__ __launch_bounds__(256) void ema_kernel(float* __restrict__ Y,
                                                  const float* __restrict__ halo) {
    const int bx = blockIdx.x;            // 16*32*2 = 1024
    const int s = bx >> 6;                // strip 0..15
    const int b = (bx >> 1) & 31;
    const int o = ((bx & 1) << 8) + threadIdx.x;

    float v = 0.f;
    if (s > 0) {
        const float* h = halo + ((size_t)(s - 1) * TAPS * B_DIM + b) * O_DIM + o;
        #pragma unroll
        for (int j = 0; j < TAPS; ++j)
            v = PARAM * v + h[(size_t)j * BO];
    }
    float* y = Y + ((size_t)s * STRIP * B_DIM + b) * O_DIM + o;
    for (int i = 0; i < STRIP; i += 8) {
        float yv[8];
        #pragma unroll
        for (int j = 0; j < 8; ++j) yv[j] = y[(size_t)(i + j) * BO];
        #pragma unroll
        for (int j = 0; j < 8; ++j) { v = PARAM * v + yv[j]; yv[j] = v; }
        #pragma unroll
        for (int j = 0; j < 8; ++j) y[(size_t)(i + j) * BO] = yv[j];
    }
}

extern "C" void kernel_launch(void* const* d_in, const int* in_sizes, int n_in,
                              void* d_out, int out_size, void* d_ws, size_t ws_size,
                              hipStream_t stream) {
    const float* X    = (const float*)d_in[0];
    const float* W    = (const float*)d_in[1];
    const float* bias = (const float*)d_in[2];
    float* Y    = (float*)d_out;
    float* halo = (float*)d_ws;
    unsigned short* Wb = (unsigned short*)((char*)d_ws + HALO_BYTES);

    wcvt_kernel<<<dim3(O_DIM * I_DIM / (256 * 4)), dim3(256), 0, stream>>>(W, Wb);
    gemm_kernel<<<dim3((M_DIM / BM) * (O_DIM / BN)), dim3(256), 0, stream>>>(X, Wb, bias, Y, halo);
    ema_kernel<<<dim3((T_DIM / STRIP) * B_DIM * (O_DIM / 256)), dim3(256), 0, stream>>>(Y, halo);
}

// Round 3
// 315.358 us; speedup vs baseline: 1.1421x; 1.0987x over previous
//
#include <hip/hip_runtime.h>
#include <hip/hip_bf16.h>

#define T_DIM 4096
#define B_DIM 32
#define I_DIM 512
#define O_DIM 512
#define M_DIM (T_DIM * B_DIM)   // 131072
#define PARAM 0.1f

#define BM 512
#define BN 128
#define STRIP 256
#define TAPS 16
#define BO (B_DIM * O_DIM)      // 16384

// ws layout: [halo: 240*32*512 f32 = 15,728,640 B][Wbf16: 512*512 u16 = 524,288 B]
#define HALO_BYTES (240u * 32u * 512u * 4u)

typedef __attribute__((ext_vector_type(8))) short bf16x8;
typedef __attribute__((ext_vector_type(4))) float f32x4;

// fp32 -> bf16 via hardware cvt (compiler emits v_cvt_pk_bf16_f32 for pairs)
__device__ __forceinline__ unsigned short f2bf(float f) {
    union { __hip_bfloat16 b; unsigned short u; } cv;
    cv.b = __float2bfloat16(f);
    return cv.u;
}

// --- W fp32 -> bf16 precompute (one-time per call, ~0.5 MB) ---
__global__ __launch_bounds__(256) void wcvt_kernel(const float* __restrict__ W,
                                                   unsigned short* __restrict__ Wb) {
    const int i = (blockIdx.x * 256 + threadIdx.x) * 4;
    f32x4 v = *(const f32x4*)(W + i);
    ushort4 o;
    o.x = f2bf(v[0]); o.y = f2bf(v[1]); o.z = f2bf(v[2]); o.w = f2bf(v[3]);
    *(ushort4*)(Wb + i) = o;
}

// GEMM: 8 waves/block, wave-tile 64x128. Full 128x512 bf16 W panel staged in LDS
// ONCE (single barrier), then barrier-free K-loop: A direct global->reg with
// 1-deep prefetch, B from swizzled LDS, 32 MFMA per k-step per wave.
__global__ __launch_bounds__(512, 2) void gemm_kernel(const float* __restrict__ X,
                                                      const unsigned short* __restrict__ Wb,
                                                      const float* __restrict__ bias,
                                                      float* __restrict__ Y,
                                                      float* __restrict__ halo) {
    __shared__ __align__(16) short Bs[BN * I_DIM];   // 128 KB

    const int tid  = threadIdx.x;
    const int lane = tid & 63;
    const int wave = tid >> 6;          // 0..7

    // XCD grouping: all 4 bn-blocks of an M-chunk land on one XCD (bid&7 = HW xcd).
    const int bid = blockIdx.x;         // 1024 blocks
    const int jj  = bid >> 3;           // 0..127
    const int bn  = jj & 3;
    const int m   = (bid & 7) * 32 + (jj >> 2);   // 0..255
    const int row0 = m * BM;
    const int col0 = bn * BN;

    // Stage full B panel via global_load_lds; source pre-swizzled with the
    // involution c ^= (r&7) so the linear LDS write lands bank-conflict-free
    // for the ds_read pattern (rule #21: same permutation both sides).
    #pragma unroll
    for (int it = 0; it < 16; ++it) {
        const int g  = it * 512 + tid;  // chunk id, 16B chunks
        const int r  = g >> 6;          // row 0..127
        const int c  = g & 63;          // chunk within 1KB row
        const int cs = c ^ (r & 7);
        const unsigned short* gsrc = Wb + (size_t)(col0 + r) * I_DIM + cs * 8;
        __builtin_amdgcn_global_load_lds(
            (const __attribute__((address_space(1))) unsigned int*)gsrc,
            (__attribute__((address_space(3))) unsigned int*)(Bs + (size_t)(it * 512 + wave * 64) * 8),
            16, 0, 0);
    }

    // A fragment base: row = row0 + wave*64 + mf*16 + (lane&15), k = ks*32 + (lane>>4)*8
    const float* aBase = X + (size_t)(row0 + wave * 64 + (lane & 15)) * I_DIM + ((lane >> 4) << 3);
    f32x4 araw[8];
    #pragma unroll
    for (int mf = 0; mf < 4; ++mf) {
        araw[2 * mf]     = *(const f32x4*)(aBase + mf * 16 * I_DIM);
        araw[2 * mf + 1] = *(const f32x4*)(aBase + mf * 16 * I_DIM + 4);
    }

    __syncthreads();   // drains vmcnt(0): B panel + A(0) ready. Last barrier.

    f32x4 acc[4][8] = {};

    #pragma unroll
    for (int ks = 0; ks < 16; ++ks) {
        // convert prefetched A (loads completed during previous iteration's MFMAs)
        bf16x8 a_cur[4];
        #pragma unroll
        for (int mf = 0; mf < 4; ++mf) {
            bf16x8 pk;
            #pragma unroll
            for (int e = 0; e < 4; ++e) {
                pk[e]     = (short)f2bf(araw[2 * mf][e]);
                pk[e + 4] = (short)f2bf(araw[2 * mf + 1][e]);
            }
            a_cur[mf] = pk;
        }
        // issue next k-step's A loads (1-deep prefetch)
        if (ks < 15) {
            #pragma unroll
            for (int mf = 0; mf < 4; ++mf) {
                araw[2 * mf]     = *(const f32x4*)(aBase + mf * 16 * I_DIM + (ks + 1) * 32);
                araw[2 * mf + 1] = *(const f32x4*)(aBase + mf * 16 * I_DIM + (ks + 1) * 32 + 4);
            }
        }
        // B fragments from LDS + MFMA, split in halves to limit register pressure
        #pragma unroll
        for (int half = 0; half < 2; ++half) {
            bf16x8 bfrag[4];
            #pragma unroll
            for (int n4 = 0; n4 < 4; ++n4) {
                const int nf = half * 4 + n4;
                const int r  = nf * 16 + (lane & 15);
                const int c  = ks * 4 + (lane >> 4);
                bfrag[n4] = *(const bf16x8*)((const char*)Bs + r * 1024 + ((c ^ (r & 7)) << 4));
            }
            #pragma unroll
            for (int mf = 0; mf < 4; ++mf)
                #pragma unroll
                for (int n4 = 0; n4 < 4; ++n4)
                    acc[mf][half * 4 + n4] = __builtin_amdgcn_mfma_f32_16x16x32_bf16(
                        a_cur[mf], bfrag[n4], acc[mf][half * 4 + n4], 0, 0, 0);
        }
    }

    // Epilogue: bias add, Y store, strip warm-up halo rows to ws.
    #pragma unroll
    for (int mf = 0; mf < 4; ++mf) {
        #pragma unroll
        for (int nf = 0; nf < 8; ++nf) {
            const int gcol = col0 + nf * 16 + (lane & 15);
            const float bv = bias[gcol];
            #pragma unroll
            for (int j = 0; j < 4; ++j) {
                const int grow = row0 + wave * 64 + mf * 16 + ((lane >> 4) << 2) + j;
                const float val = acc[mf][nf][j] + bv;
                Y[(size_t)grow * O_DIM + gcol] = val;
                const int t = grow >> 5;   // row = t*32 + b
                if ((t & (STRIP - 1)) >= (STRIP - TAPS) && t < (T_DIM - STRIP)) {
                    const int ht = ((t >> 8) << 4) + (t & (STRIP - 1)) - (STRIP - TAPS);
                    const int bb = grow & 31;
                    halo[((size_t)ht * B_DIM + bb) * O_DIM + gcol] = val;
                }
            }
        }
    }
}

// EMA over t, in-place on Y. Strip s>0 warm-starts from 16 halo rows
// (p^16 = 1e-16 -> truncation error far below fp32 resolution).
__global__ __launch_bounds__(256) void ema_kernel(float* __restrict__ Y,
                                                  const float* __restrict__ halo) {
    const int bx = blockIdx.x;            // 16*32*2 = 1024
    const int s = bx >> 6;                // strip 0..15
    const int b = (bx >> 1) & 31;
    const int o = ((bx & 1) << 8) + threadIdx.x;

    float v = 0.f;
    if (s > 0) {
        const float* h = halo + ((size_t)(s - 1) * TAPS * B_DIM + b) * O_DIM + o;
        #pragma unroll
        for (int j = 0; j < TAPS; ++j)
            v = PARAM * v + h[(size_t)j * BO];
    }
    float* y = Y + ((size_t)s * STRIP * B_DIM + b) * O_DIM + o;
    for (int i = 0; i < STRIP; i += 8) {
        float yv[8];
        #pragma unroll
        for (int j = 0; j < 8; ++j) yv[j] = y[(size_t)(i + j) * BO];
        #pragma unroll
        for (int j = 0; j < 8; ++j) { v = PARAM * v + yv[j]; yv[j] = v; }
        #pragma unroll
        for (int j = 0; j < 8; ++j) y[(size_t)(i + j) * BO] = yv[j];
    }
}

extern "C" void kernel_launch(void* const* d_in, const int* in_sizes, int n_in,
                              void* d_out, int out_size, void* d_ws, size_t ws_size,
                              hipStream_t stream) {
    const float* X    = (const float*)d_in[0];
    const float* W    = (const float*)d_in[1];
    const float* bias = (const float*)d_in[2];
    float* Y    = (float*)d_out;
    float* halo = (float*)d_ws;
    unsigned short* Wb = (unsigned short*)((char*)d_ws + HALO_BYTES);

    wcvt_kernel<<<dim3(O_DIM * I_DIM / (256 * 4)), dim3(256), 0, stream>>>(W, Wb);
    gemm_kernel<<<dim3((M_DIM / BM) * (O_DIM / BN)), dim3(512), 0, stream>>>(X, Wb, bias, Y, halo);
    ema_kernel<<<dim3((T_DIM / STRIP) * B_DIM * (O_DIM / 256)), dim3(256), 0, stream>>>(Y, halo);
}

// Round 4
// 297.239 us; speedup vs baseline: 1.2117x; 1.0610x over previous
//
#include <hip/hip_runtime.h>
#include <hip/hip_bf16.h>

#define T_DIM 4096
#define B_DIM 32
#define I_DIM 512
#define O_DIM 512
#define M_DIM (T_DIM * B_DIM)   // 131072
#define PARAM 0.1f
#define ISCALE 1.1111112f       // 1/(1-p)

#define STRIP 128
#define TAPS 8                  // p^8 = 1e-8 << bf16 eps of Xv

#define BM 128
#define BN 512

typedef __attribute__((ext_vector_type(8))) short bf16x8;
typedef __attribute__((ext_vector_type(4))) float f32x4;

__device__ __forceinline__ unsigned short f2bf(float f) {
    union { __hip_bfloat16 b; unsigned short u; } cv;
    cv.b = __float2bfloat16(f);
    return cv.u;
}

// --- W fp32 -> bf16 precompute (0.5 MB, into d_ws) ---
__global__ __launch_bounds__(256) void wcvt_kernel(const float* __restrict__ W,
                                                   unsigned short* __restrict__ Wb) {
    const int i = (blockIdx.x * 256 + threadIdx.x) * 4;
    f32x4 v = *(const f32x4*)(W + i);
    ushort4 o;
    o.x = f2bf(v[0]); o.y = f2bf(v[1]); o.z = f2bf(v[2]); o.w = f2bf(v[3]);
    *(ushort4*)(Wb + i) = o;
}

// --- EMA over raw X (linearity: EMA(XW+b) = EMA(X)W + s[t]*b). Strip-parallel,
// warm-up reads TAPS raw rows. Output bf16 into the FIRST 1KB of each 2KB
// row-slot of d_out; the GEMM stages from there and overwrites only its own
// rows -> race-free regardless of dispatch order. ---
__global__ __launch_bounds__(256) void xema_kernel(const float* __restrict__ X,
                                                   unsigned short* __restrict__ Xv) {
    const int s   = blockIdx.x >> 4;                 // strip 0..31
    const int blk = blockIdx.x & 15;
    const int col = (blk * 256 + threadIdx.x) * 4;   // 0..16380 within [b][o] plane
    const int t0  = s * STRIP;
    const int b   = col >> 9;
    const int o   = col & 511;

    const float* xin = X + (size_t)t0 * 16384 + col;             // stride 16384/t
    unsigned short* xout = Xv + ((size_t)(t0 * 32 + b)) * 1024 + o; // stride 32768/t

    f32x4 v = {0.f, 0.f, 0.f, 0.f};
    if (s > 0) {
        const float* w = xin - (size_t)TAPS * 16384;
        #pragma unroll
        for (int j = 0; j < TAPS; ++j)
            v = PARAM * v + *(const f32x4*)(w + (size_t)j * 16384);
    }

    f32x4 bufA[8], bufB[8];
    #pragma unroll
    for (int j = 0; j < 8; ++j) bufA[j] = *(const f32x4*)(xin + (size_t)j * 16384);

    #pragma unroll
    for (int i = 0; i < STRIP; i += 16) {
        #pragma unroll
        for (int j = 0; j < 8; ++j)
            bufB[j] = *(const f32x4*)(xin + (size_t)(i + 8 + j) * 16384);
        #pragma unroll
        for (int j = 0; j < 8; ++j) {
            v = PARAM * v + bufA[j];
            ushort4 pk; pk.x = f2bf(v[0]); pk.y = f2bf(v[1]); pk.z = f2bf(v[2]); pk.w = f2bf(v[3]);
            *(ushort4*)(xout + (size_t)(i + j) * 32768) = pk;
        }
        if (i + 16 < STRIP) {
            #pragma unroll
            for (int j = 0; j < 8; ++j)
                bufA[j] = *(const f32x4*)(xin + (size_t)(i + 16 + j) * 16384);
        }
        #pragma unroll
        for (int j = 0; j < 8; ++j) {
            v = PARAM * v + bufB[j];
            ushort4 pk; pk.x = f2bf(v[0]); pk.y = f2bf(v[1]); pk.z = f2bf(v[2]); pk.w = f2bf(v[3]);
            *(ushort4*)(xout + (size_t)(i + 8 + j) * 32768) = pk;
        }
    }
}

// --- GEMM: BM=128 x BN=512 (full N -> zero A redundancy). A panel 128KB bf16
// staged ONCE via global_load_lds (pre-swizzled source, involution c^(r&7)),
// B streamed from L2-hot 512KB Wb with 1-step reg double-buffer. Barrier-free
// K-loop. Epilogue: Y = acc + s[t]*bias, overwriting this block's own rows. ---
__global__ __launch_bounds__(512, 2) void gemm_kernel(const unsigned short* Xv,
                                                      const unsigned short* __restrict__ Wb,
                                                      const float* __restrict__ bias,
                                                      float* Y) {
    __shared__ __align__(16) short As[BM * I_DIM];   // 128 KB

    const int tid  = threadIdx.x;
    const int lane = tid & 63;
    const int wave = tid >> 6;
    const int row0 = blockIdx.x * BM;
    const int wm = wave >> 2;         // 0..1 (64 rows)
    const int wn = wave & 3;          // 0..3 (128 cols)

    // Stage A panel: Xv row r lives at ushort offset (row0+r)*1024, 64 chunks of 16B.
    #pragma unroll
    for (int it = 0; it < 16; ++it) {
        const int g  = it * 512 + tid;   // chunk id 0..8191
        const int r  = g >> 6;
        const int c  = g & 63;
        const int cs = c ^ (r & 7);
        const unsigned short* gsrc = Xv + (size_t)(row0 + r) * 1024 + cs * 8;
        __builtin_amdgcn_global_load_lds(
            (const __attribute__((address_space(1))) unsigned int*)gsrc,
            (__attribute__((address_space(3))) unsigned int*)(As + (size_t)(it * 512 + wave * 64) * 8),
            16, 0, 0);
    }

    const unsigned short* bBase = Wb + (size_t)(wn * 128 + (lane & 15)) * 512 + ((lane >> 4) << 3);

    bf16x8 b0[8], b1[8];
    #pragma unroll
    for (int nf = 0; nf < 8; ++nf)
        b0[nf] = *(const bf16x8*)(bBase + (size_t)nf * 8192);

    __syncthreads();   // drains stage + b0. Only barrier.

    f32x4 acc[4][8] = {};

    #pragma unroll
    for (int ks = 0; ks < 16; ks += 2) {
        #pragma unroll
        for (int nf = 0; nf < 8; ++nf)
            b1[nf] = *(const bf16x8*)(bBase + (size_t)nf * 8192 + (ks + 1) * 32);
        {
            bf16x8 a[4];
            #pragma unroll
            for (int mf = 0; mf < 4; ++mf) {
                const int r = wm * 64 + mf * 16 + (lane & 15);
                const int c = ks * 4 + (lane >> 4);
                a[mf] = *(const bf16x8*)((const char*)As + r * 1024 + ((c ^ (r & 7)) << 4));
            }
            #pragma unroll
            for (int mf = 0; mf < 4; ++mf)
                #pragma unroll
                for (int nf = 0; nf < 8; ++nf)
                    acc[mf][nf] = __builtin_amdgcn_mfma_f32_16x16x32_bf16(a[mf], b0[nf], acc[mf][nf], 0, 0, 0);
        }
        if (ks + 2 < 16) {
            #pragma unroll
            for (int nf = 0; nf < 8; ++nf)
                b0[nf] = *(const bf16x8*)(bBase + (size_t)nf * 8192 + (ks + 2) * 32);
        }
        {
            bf16x8 a[4];
            #pragma unroll
            for (int mf = 0; mf < 4; ++mf) {
                const int r = wm * 64 + mf * 16 + (lane & 15);
                const int c = (ks + 1) * 4 + (lane >> 4);
                a[mf] = *(const bf16x8*)((const char*)As + r * 1024 + ((c ^ (r & 7)) << 4));
            }
            #pragma unroll
            for (int mf = 0; mf < 4; ++mf)
                #pragma unroll
                for (int nf = 0; nf < 8; ++nf)
                    acc[mf][nf] = __builtin_amdgcn_mfma_f32_16x16x32_bf16(a[mf], b1[nf], acc[mf][nf], 0, 0, 0);
        }
    }

    // bias EMA-scale s[t] = (1 - p^(t+1))/(1-p); depends on (mf, j) only.
    float sc[4][4];
    #pragma unroll
    for (int mf = 0; mf < 4; ++mf)
        #pragma unroll
        for (int j = 0; j < 4; ++j) {
            const int t = (row0 + wm * 64 + mf * 16 + ((lane >> 4) << 2) + j) >> 5;
            sc[mf][j] = (1.0f - __expf(-2.3025851f * (float)(t + 1))) * ISCALE;
        }

    #pragma unroll
    for (int mf = 0; mf < 4; ++mf) {
        #pragma unroll
        for (int nf = 0; nf < 8; ++nf) {
            const int gcol = wn * 128 + nf * 16 + (lane & 15);
            const float bv = bias[gcol];
            #pragma unroll
            for (int j = 0; j < 4; ++j) {
                const int grow = row0 + wm * 64 + mf * 16 + ((lane >> 4) << 2) + j;
                Y[(size_t)grow * O_DIM + gcol] = acc[mf][nf][j] + sc[mf][j] * bv;
            }
        }
    }
}

extern "C" void kernel_launch(void* const* d_in, const int* in_sizes, int n_in,
                              void* d_out, int out_size, void* d_ws, size_t ws_size,
                              hipStream_t stream) {
    const float* X    = (const float*)d_in[0];
    const float* W    = (const float*)d_in[1];
    const float* bias = (const float*)d_in[2];
    float* Y = (float*)d_out;
    unsigned short* Wb = (unsigned short*)d_ws;          // 0.5 MB
    unsigned short* Xv = (unsigned short*)d_out;         // bf16, first 1KB of each 2KB row-slot

    wcvt_kernel<<<dim3(O_DIM * I_DIM / (256 * 4)), dim3(256), 0, stream>>>(W, Wb);
    xema_kernel<<<dim3((T_DIM / STRIP) * 16), dim3(256), 0, stream>>>(X, Xv);
    gemm_kernel<<<dim3(M_DIM / BM), dim3(512), 0, stream>>>(Xv, Wb, bias, Y);
}

// Round 5
// 234.367 us; speedup vs baseline: 1.5368x; 1.2683x over previous
//
#include <hip/hip_runtime.h>
#include <hip/hip_bf16.h>

#define T_DIM 4096
#define B_DIM 32
#define I_DIM 512
#define O_DIM 512
#define M_DIM (T_DIM * B_DIM)   // 131072
#define PARAM 0.1f
#define ISCALE 1.1111112f       // 1/(1-p)

#define STRIP 128
#define TAPS 8                  // p^8 = 1e-8 << bf16 eps of Xv

#define BM 64
#define BN 512
#define BK 64

typedef __attribute__((ext_vector_type(8))) short bf16x8;
typedef __attribute__((ext_vector_type(4))) float f32x4;

__device__ __forceinline__ unsigned short f2bf(float f) {
    union { __hip_bfloat16 b; unsigned short u; } cv;
    cv.b = __float2bfloat16(f);
    return cv.u;
}

// --- W fp32 -> bf16 precompute (0.5 MB, into d_ws) ---
__global__ __launch_bounds__(256) void wcvt_kernel(const float* __restrict__ W,
                                                   unsigned short* __restrict__ Wb) {
    const int i = (blockIdx.x * 256 + threadIdx.x) * 4;
    f32x4 v = *(const f32x4*)(W + i);
    ushort4 o;
    o.x = f2bf(v[0]); o.y = f2bf(v[1]); o.z = f2bf(v[2]); o.w = f2bf(v[3]);
    *(ushort4*)(Wb + i) = o;
}

// --- EMA over raw X (linearity: EMA(XW+b) = EMA(X)W + s[t]*b). Strip-parallel,
// warm-up reads TAPS raw rows. Output bf16 into the first 1KB of each 2KB
// row-slot of d_out; GEMM blocks own full rows (BN=512) -> race-free. ---
__global__ __launch_bounds__(256) void xema_kernel(const float* __restrict__ X,
                                                   unsigned short* __restrict__ Xv) {
    const int s   = blockIdx.x >> 4;                 // strip 0..31
    const int blk = blockIdx.x & 15;
    const int col = (blk * 256 + threadIdx.x) * 4;   // within [b][o] plane
    const int t0  = s * STRIP;
    const int b   = col >> 9;
    const int o   = col & 511;

    const float* xin = X + (size_t)t0 * 16384 + col;
    unsigned short* xout = Xv + ((size_t)(t0 * 32 + b)) * 1024 + o;

    f32x4 v = {0.f, 0.f, 0.f, 0.f};
    if (s > 0) {
        const float* w = xin - (size_t)TAPS * 16384;
        #pragma unroll
        for (int j = 0; j < TAPS; ++j)
            v = PARAM * v + *(const f32x4*)(w + (size_t)j * 16384);
    }

    f32x4 bufA[8], bufB[8];
    #pragma unroll
    for (int j = 0; j < 8; ++j) bufA[j] = *(const f32x4*)(xin + (size_t)j * 16384);

    #pragma unroll
    for (int i = 0; i < STRIP; i += 16) {
        #pragma unroll
        for (int j = 0; j < 8; ++j)
            bufB[j] = *(const f32x4*)(xin + (size_t)(i + 8 + j) * 16384);
        #pragma unroll
        for (int j = 0; j < 8; ++j) {
            v = PARAM * v + bufA[j];
            ushort4 pk; pk.x = f2bf(v[0]); pk.y = f2bf(v[1]); pk.z = f2bf(v[2]); pk.w = f2bf(v[3]);
            *(ushort4*)(xout + (size_t)(i + j) * 32768) = pk;
        }
        if (i + 16 < STRIP) {
            #pragma unroll
            for (int j = 0; j < 8; ++j)
                bufA[j] = *(const f32x4*)(xin + (size_t)(i + 16 + j) * 16384);
        }
        #pragma unroll
        for (int j = 0; j < 8; ++j) {
            v = PARAM * v + bufB[j];
            ushort4 pk; pk.x = f2bf(v[0]); pk.y = f2bf(v[1]); pk.z = f2bf(v[2]); pk.w = f2bf(v[3]);
            *(ushort4*)(xout + (size_t)(i + 8 + j) * 32768) = pk;
        }
    }
}

// --- GEMM: BM=64 x BN=512 (full N -> zero A redundancy, race-free row ownership).
// m97 2-barrier loop, A+B tiles via global_load_lds (pre-swizzled src), LDS 72KB
// single-buffer -> 2 blocks/CU (4 waves/SIMD) so drains overlap across blocks. ---
__global__ __launch_bounds__(512, 4) void gemm_kernel(const unsigned short* Xv,
                                                      const unsigned short* __restrict__ Wb,
                                                      const float* __restrict__ bias,
                                                      float* Y) {
    __shared__ __align__(16) short As[BM * BK];   //  8 KB
    __shared__ __align__(16) short Bs[BN * BK];   // 64 KB

    const int tid  = threadIdx.x;
    const int lane = tid & 63;
    const int wave = tid >> 6;        // = wn, 0..7
    const int row0 = blockIdx.x * BM;

    // Staging geometry: chunk = set*512 + wave*64 + lane; r = chunk>>3, c = lane&7.
    // r&7 == lane>>3 for every set -> swizzled chunk cs is per-thread constant.
    const int cs   = (lane & 7) ^ (lane >> 3);
    const int rA   = wave * 8 + (lane >> 3);            // A row this thread stages
    const unsigned short* aSrc = Xv + (size_t)(row0 + rA) * 1024 + cs * 8;
    const unsigned short* bSrc = Wb + (size_t)(wave * 8 + (lane >> 3)) * 512 + cs * 8;

    f32x4 acc[4][4] = {};

    for (int ks = 0; ks < I_DIM / BK; ++ks) {
        const int k0 = ks * BK;
        // stage A (1 chunk/thread)
        __builtin_amdgcn_global_load_lds(
            (const __attribute__((address_space(1))) unsigned int*)(aSrc + k0),
            (__attribute__((address_space(3))) unsigned int*)(As + (size_t)(wave * 64) * 8),
            16, 0, 0);
        // stage B (8 chunks/thread, row stride 64 per set)
        #pragma unroll
        for (int i = 0; i < 8; ++i) {
            __builtin_amdgcn_global_load_lds(
                (const __attribute__((address_space(1))) unsigned int*)(bSrc + (size_t)i * 64 * 512 + k0),
                (__attribute__((address_space(3))) unsigned int*)(Bs + (size_t)(i * 512 + wave * 64) * 8),
                16, 0, 0);
        }
        __syncthreads();   // drains vmcnt(0)

        #pragma unroll
        for (int kk = 0; kk < 2; ++kk) {
            const int cc = kk * 4 + (lane >> 4);
            bf16x8 a[4], b[4];
            #pragma unroll
            for (int mf = 0; mf < 4; ++mf) {
                const int r = mf * 16 + (lane & 15);
                a[mf] = *(const bf16x8*)((const char*)As + r * 128 + ((cc ^ (r & 7)) << 4));
            }
            #pragma unroll
            for (int nf = 0; nf < 4; ++nf) {
                const int r = wave * 64 + nf * 16 + (lane & 15);
                b[nf] = *(const bf16x8*)((const char*)Bs + r * 128 + ((cc ^ (r & 7)) << 4));
            }
            #pragma unroll
            for (int mf = 0; mf < 4; ++mf)
                #pragma unroll
                for (int nf = 0; nf < 4; ++nf)
                    acc[mf][nf] = __builtin_amdgcn_mfma_f32_16x16x32_bf16(
                        a[mf], b[nf], acc[mf][nf], 0, 0, 0);
        }
        __syncthreads();
    }

    // bias EMA-scale s[t] = (1 - p^(t+1))/(1-p); t depends on (mf, j) only.
    float sc[4][4];
    #pragma unroll
    for (int mf = 0; mf < 4; ++mf)
        #pragma unroll
        for (int j = 0; j < 4; ++j) {
            const int t = (row0 + mf * 16 + ((lane >> 4) << 2) + j) >> 5;
            sc[mf][j] = (1.0f - __expf(-2.3025851f * (float)(t + 1))) * ISCALE;
        }

    #pragma unroll
    for (int mf = 0; mf < 4; ++mf) {
        #pragma unroll
        for (int nf = 0; nf < 4; ++nf) {
            const int gcol = wave * 64 + nf * 16 + (lane & 15);
            const float bv = bias[gcol];
            #pragma unroll
            for (int j = 0; j < 4; ++j) {
                const int grow = row0 + mf * 16 + ((lane >> 4) << 2) + j;
                Y[(size_t)grow * O_DIM + gcol] = acc[mf][nf][j] + sc[mf][j] * bv;
            }
        }
    }
}

extern "C" void kernel_launch(void* const* d_in, const int* in_sizes, int n_in,
                              void* d_out, int out_size, void* d_ws, size_t ws_size,
                              hipStream_t stream) {
    const float* X    = (const float*)d_in[0];
    const float* W    = (const float*)d_in[1];
    const float* bias = (const float*)d_in[2];
    float* Y = (float*)d_out;
    unsigned short* Wb = (unsigned short*)d_ws;          // 0.5 MB
    unsigned short* Xv = (unsigned short*)d_out;         // bf16 in first 1KB of each 2KB row-slot

    wcvt_kernel<<<dim3(O_DIM * I_DIM / (256 * 4)), dim3(256), 0, stream>>>(W, Wb);
    xema_kernel<<<dim3((T_DIM / STRIP) * 16), dim3(256), 0, stream>>>(X, Xv);
    gemm_kernel<<<dim3(M_DIM / BM), dim3(512), 0, stream>>>(Xv, Wb, bias, Y);
}